// Round 1
// baseline (125.040 us; speedup 1.0000x reference)
//
#include <hip/hip_runtime.h>
#include <math.h>

// Problem constants (from reference)
#define NB 32      // batch
#define NN 8192    // neighbors
#define DD 384     // feature dim
#define LL 128     // latent dim
#define CHUNKS 32  // blocks per batch in stream kernel
#define RPB 256    // rows per block (NN/CHUNKS)
#define NWAVES 4   // waves per block
#define RPW 64     // rows per wave

// Workspace layout (floats):
//  [0]           : mask-format flag (int)
//  [64 ..)       : u[32*384]   (scaled Wk@q per batch)
//  then c[32], pm[1024], ps[1024], pa[1024*384]   (~1.63 MB total)

// ---------------------------------------------------------------------------
// Kernel A: per-batch q = target@Wq+bq (internal), then u = scale*(Wk@q),
// c = scale*(bk.q). Block 0 also probes the mask dtype encoding.
// ---------------------------------------------------------------------------
__global__ __launch_bounds__(384) void ga_prep(
    const float* __restrict__ target,
    const float* __restrict__ Wq, const float* __restrict__ bq,
    const float* __restrict__ Wk, const float* __restrict__ bk,
    const void* __restrict__ mask,
    float* __restrict__ u, float* __restrict__ c, int* __restrict__ flag)
{
    const int b = blockIdx.x;   // 32 blocks
    const int t = threadIdx.x;  // 384 threads

    __shared__ float tgt[DD];
    __shared__ float qp[3][LL];
    __shared__ float qs[LL];
    __shared__ int s_notint, s_notflt;

    if (b == 0 && t == 0) { s_notint = 0; s_notflt = 0; }
    tgt[t] = target[b * DD + t];
    __syncthreads();

    // Mask dtype probe (block 0 only): int32 {0,1} vs float32 {0,1.0f} vs bytes
    if (b == 0 && t < 256) {
        unsigned v = ((const unsigned*)mask)[t];
        if (v > 1u) s_notint = 1;                       // benign race, all write 1
        if (v != 0u && v != 0x3F800000u) s_notflt = 1;
    }

    // q[l] = bq[l] + sum_d tgt[d]*Wq[d*128+l], split d into 3 segments
    const int l = t & (LL - 1);
    const int seg = t >> 7;  // 0..2
    float acc = 0.f;
#pragma unroll 4
    for (int i = 0; i < 128; ++i) {
        int d = seg * 128 + i;
        acc += tgt[d] * Wq[d * LL + l];  // coalesced across l
    }
    qp[seg][l] = acc;
    __syncthreads();
    if (t < LL) qs[t] = qp[0][t] + qp[1][t] + qp[2][t] + bq[t];
    __syncthreads();

    const float scale = 0.051031036307982884f;  // 1/sqrt(384)
    if (t == 0) {
        float cc = 0.f;
        for (int i = 0; i < LL; ++i) cc += bk[i] * qs[i];
        c[b] = cc * scale;
    }

    // u[d] = scale * sum_l Wk[d*128+l]*q[l]; thread t owns d=t
    float au = 0.f;
#pragma unroll 4
    for (int i = 0; i < LL; ++i) au += Wk[t * LL + i] * qs[i];
    u[b * DD + t] = au * scale;

    __syncthreads();
    if (b == 0 && t == 0) *flag = s_notint ? (s_notflt ? 2 : 1) : 0;
}

// ---------------------------------------------------------------------------
// Kernel B: stream h once. One row per wave per iteration; wave-uniform mask
// skip; online softmax with 384-wide accumulator (6 f32/lane). Block-level
// merge in LDS -> per-block partial (m, s, a[384]).
// ---------------------------------------------------------------------------
__global__ __launch_bounds__(256) void ga_stream(
    const float* __restrict__ h, const void* __restrict__ mask,
    const float* __restrict__ u, const float* __restrict__ c,
    const int* __restrict__ flag,
    float* __restrict__ pm, float* __restrict__ ps, float* __restrict__ pa)
{
    const int blk = blockIdx.x;           // 1024 blocks
    const int b = blk >> 5;               // batch
    const int chunk = blk & (CHUNKS - 1);
    const int wave = threadIdx.x >> 6;
    const int lane = threadIdx.x & 63;

    // u fragment: lane owns elems {2l,2l+1} of each 128-segment
    const float* ub = u + b * DD;
    const float2 uv0 = *(const float2*)(ub + 2 * lane);
    const float2 uv1 = *(const float2*)(ub + 128 + 2 * lane);
    const float2 uv2 = *(const float2*)(ub + 256 + 2 * lane);
    const float cc = c[b];

    const int n0 = chunk * RPB + wave * RPW;
    const size_t rowbase = (size_t)b * NN + n0;
    const float* hb = h + rowbase * DD;

    // Pre-gather this wave's 64 mask values -> one ballot bitmask (SGPR)
    const int fm = *flag;
    int myMask;
    const size_t mi = rowbase + lane;
    if (fm == 0)      myMask = ((const int*)mask)[mi] != 0;
    else if (fm == 1) myMask = ((const unsigned*)mask)[mi] != 0u;
    else              myMask = ((const unsigned char*)mask)[mi] != 0;
    const unsigned long long mbits = __ballot(myMask);

    float m = -INFINITY, s = 0.f;
    float a0 = 0.f, a1 = 0.f, a2 = 0.f, a3 = 0.f, a4 = 0.f, a5 = 0.f;

    for (int r = 0; r < RPW; ++r) {
        if (!((mbits >> r) & 1ull)) continue;  // wave-uniform skip
        const float* row = hb + (size_t)r * DD;
        float2 x0 = *(const float2*)(row + 2 * lane);
        float2 x1 = *(const float2*)(row + 128 + 2 * lane);
        float2 x2 = *(const float2*)(row + 256 + 2 * lane);
        float d = x0.x * uv0.x + x0.y * uv0.y + x1.x * uv1.x + x1.y * uv1.y +
                  x2.x * uv2.x + x2.y * uv2.y;
#pragma unroll
        for (int off = 32; off; off >>= 1) d += __shfl_xor(d, off, 64);
        float score = d + cc;
        if (score > m) {  // uniform: score identical on all lanes post-reduce
            float f = __expf(m - score);
            s *= f; a0 *= f; a1 *= f; a2 *= f; a3 *= f; a4 *= f; a5 *= f;
            m = score;
        }
        float p = __expf(score - m);
        s += p;
        a0 += p * x0.x; a1 += p * x0.y;
        a2 += p * x1.x; a3 += p * x1.y;
        a4 += p * x2.x; a5 += p * x2.y;
    }

    __shared__ float lm[NWAVES], lss[NWAVES];
    __shared__ float la[NWAVES][DD];
    la[wave][2 * lane] = a0;       la[wave][2 * lane + 1] = a1;
    la[wave][128 + 2 * lane] = a2; la[wave][128 + 2 * lane + 1] = a3;
    la[wave][256 + 2 * lane] = a4; la[wave][256 + 2 * lane + 1] = a5;
    if (lane == 0) { lm[wave] = m; lss[wave] = s; }
    __syncthreads();

    const float M = fmaxf(fmaxf(lm[0], lm[1]), fmaxf(lm[2], lm[3]));
    const float w0 = (lm[0] == -INFINITY) ? 0.f : __expf(lm[0] - M);
    const float w1 = (lm[1] == -INFINITY) ? 0.f : __expf(lm[1] - M);
    const float w2 = (lm[2] == -INFINITY) ? 0.f : __expf(lm[2] - M);
    const float w3 = (lm[3] == -INFINITY) ? 0.f : __expf(lm[3] - M);
    const float S = w0 * lss[0] + w1 * lss[1] + w2 * lss[2] + w3 * lss[3];
    if (threadIdx.x == 0) { pm[blk] = M; ps[blk] = S; }
    for (int idx = threadIdx.x; idx < DD; idx += 256) {
        pa[(size_t)blk * DD + idx] =
            w0 * la[0][idx] + w1 * la[1][idx] + w2 * la[2][idx] + w3 * la[3][idx];
    }
}

// ---------------------------------------------------------------------------
// Kernel C: per batch, reduce 32 partials -> a_norm[384]; nws = a_norm@Wv+bv;
// z=[nws,target]; out = relu(z@W1+b1)@W2+b2.
// ---------------------------------------------------------------------------
__global__ __launch_bounds__(128) void ga_finish(
    const float* __restrict__ target,
    const float* __restrict__ Wv, const float* __restrict__ bv,
    const float* __restrict__ W1, const float* __restrict__ b1,
    const float* __restrict__ W2, const float* __restrict__ b2,
    const float* __restrict__ pm, const float* __restrict__ ps,
    const float* __restrict__ pa, float* __restrict__ out)
{
    const int b = blockIdx.x;   // 32 blocks
    const int t = threadIdx.x;  // 128 threads

    __shared__ float an[DD];
    __shared__ float z[LL + DD];
    __shared__ float hid[LL];

    // Global max / denom across the 32 chunk partials (redundant per thread)
    float M = -INFINITY;
#pragma unroll
    for (int i = 0; i < CHUNKS; ++i) M = fmaxf(M, pm[b * CHUNKS + i]);
    float wgt[CHUNKS];
    float S = 0.f;
#pragma unroll
    for (int i = 0; i < CHUNKS; ++i) {
        float mi = pm[b * CHUNKS + i];
        float w = (mi == -INFINITY) ? 0.f : __expf(mi - M);
        wgt[i] = w;
        S += w * ps[b * CHUNKS + i];
    }
    const float invS = 1.f / S;

    for (int d = t; d < DD; d += LL) {
        float av = 0.f;
#pragma unroll
        for (int i = 0; i < CHUNKS; ++i)
            av += wgt[i] * pa[(size_t)(b * CHUNKS + i) * DD + d];
        an[d] = av * invS;
    }
    __syncthreads();

    // nws[t] = sum_d an[d]*Wv[d*128+t] + bv[t]
    float acc = bv[t];
#pragma unroll 4
    for (int d = 0; d < DD; ++d) acc += an[d] * Wv[d * LL + t];
    z[t] = acc;
    for (int j = t; j < DD; j += LL) z[LL + j] = target[b * DD + j];
    __syncthreads();

    float hacc = b1[t];
#pragma unroll 4
    for (int j = 0; j < LL + DD; ++j) hacc += z[j] * W1[j * LL + t];
    hid[t] = fmaxf(hacc, 0.f);
    __syncthreads();

    float oacc = b2[t];
#pragma unroll 4
    for (int j = 0; j < LL; ++j) oacc += hid[j] * W2[j * LL + t];
    out[b * LL + t] = oacc;
}

// ---------------------------------------------------------------------------
extern "C" void kernel_launch(void* const* d_in, const int* in_sizes, int n_in,
                              void* d_out, int out_size, void* d_ws, size_t ws_size,
                              hipStream_t stream)
{
    const float* target = (const float*)d_in[0];
    const float* h      = (const float*)d_in[1];
    const void*  mask   = d_in[2];
    const float* Wq = (const float*)d_in[3];
    const float* bq = (const float*)d_in[4];
    const float* Wk = (const float*)d_in[5];
    const float* bk = (const float*)d_in[6];
    const float* Wv = (const float*)d_in[7];
    const float* bv = (const float*)d_in[8];
    const float* W1 = (const float*)d_in[9];
    const float* b1 = (const float*)d_in[10];
    const float* W2 = (const float*)d_in[11];
    const float* b2 = (const float*)d_in[12];
    float* out = (float*)d_out;

    float* ws = (float*)d_ws;
    int*   flag = (int*)d_ws;
    float* u  = ws + 64;
    float* c  = u + NB * DD;
    float* pm = c + NB;
    float* ps = pm + NB * CHUNKS;
    float* pa = ps + NB * CHUNKS;
    // total ws use: ~1.63 MB

    hipLaunchKernelGGL(ga_prep, dim3(NB), dim3(DD), 0, stream,
                       target, Wq, bq, Wk, bk, mask, u, c, flag);
    hipLaunchKernelGGL(ga_stream, dim3(NB * CHUNKS), dim3(256), 0, stream,
                       h, mask, u, c, flag, pm, ps, pa);
    hipLaunchKernelGGL(ga_finish, dim3(NB), dim3(LL), 0, stream,
                       target, Wv, bv, W1, b1, W2, b2, pm, ps, pa, out);
}

// Round 2
// 124.999 us; speedup vs baseline: 1.0003x; 1.0003x over previous
//
#include <hip/hip_runtime.h>
#include <math.h>

// Problem constants (from reference)
#define NB 32      // batch
#define NN 8192    // neighbors
#define DD 384     // feature dim
#define LL 128     // latent dim
#define CHUNKS 32  // blocks per batch in stream kernel
#define RPB 256    // rows per block (NN/CHUNKS)
#define NWAVES 4   // waves per block
#define RPW 64     // rows per wave

// ---------------------------------------------------------------------------
// Kernel A: per-batch q = target@Wq+bq (internal), then u = scale*(Wk@q),
// c = scale*(bk.q). Block 0 also probes the mask dtype encoding.
// ---------------------------------------------------------------------------
__global__ __launch_bounds__(384) void ga_prep(
    const float* __restrict__ target,
    const float* __restrict__ Wq, const float* __restrict__ bq,
    const float* __restrict__ Wk, const float* __restrict__ bk,
    const void* __restrict__ mask,
    float* __restrict__ u, float* __restrict__ c, int* __restrict__ flag)
{
    const int b = blockIdx.x;   // 32 blocks
    const int t = threadIdx.x;  // 384 threads

    __shared__ float tgt[DD];
    __shared__ float qp[3][LL];
    __shared__ float qs[LL];
    __shared__ int s_notint, s_notflt;

    if (b == 0 && t == 0) { s_notint = 0; s_notflt = 0; }
    tgt[t] = target[b * DD + t];
    __syncthreads();

    // Mask dtype probe (block 0 only): int32 {0,1} vs float32 vs bytes
    if (b == 0 && t < 256) {
        unsigned v = ((const unsigned*)mask)[t];
        if (v > 1u) s_notint = 1;                       // benign race, all write 1
        if (v != 0u && v != 0x3F800000u) s_notflt = 1;
    }

    // q[l] = bq[l] + sum_d tgt[d]*Wq[d*128+l], split d into 3 segments
    const int l = t & (LL - 1);
    const int seg = t >> 7;  // 0..2
    float acc = 0.f;
#pragma unroll 4
    for (int i = 0; i < 128; ++i) {
        int d = seg * 128 + i;
        acc += tgt[d] * Wq[d * LL + l];  // coalesced across l
    }
    qp[seg][l] = acc;
    __syncthreads();
    if (t < LL) qs[t] = qp[0][t] + qp[1][t] + qp[2][t] + bq[t];
    __syncthreads();

    const float scale = 0.051031036307982884f;  // 1/sqrt(384)
    if (t == 0) {
        float cc = 0.f;
        for (int i = 0; i < LL; ++i) cc += bk[i] * qs[i];
        c[b] = cc * scale;
    }

    // u[d] = scale * sum_l Wk[d*128+l]*q[l]; thread t owns d=t
    float au = 0.f;
#pragma unroll 4
    for (int i = 0; i < LL; ++i) au += Wk[t * LL + i] * qs[i];
    u[b * DD + t] = au * scale;

    __syncthreads();
    if (b == 0 && t == 0) *flag = s_notint ? (s_notflt ? 2 : 1) : 0;
}

// ---------------------------------------------------------------------------
// Kernel B: stream h once. Per wave: compact unmasked lane indices via
// ballot prefix-popcount into LDS, then process 8 rows per iteration:
// 16 independent load instrs in flight, 8 interleaved butterfly reduces,
// one online-softmax rescale per 8 rows. Block merge in LDS.
// ---------------------------------------------------------------------------

#define GA_LOAD(j) \
    const int r##j = (base + j < cnt) ? wlist[wave][base + j] : 0; \
    const float* row##j = hb + (size_t)r##j * DD; \
    const float4 xa##j = *(const float4*)(row##j + 4 * lane); \
    const float2 xb##j = *(const float2*)(row##j + 256 + 2 * lane);

#define GA_DOT(j) \
    float d##j = xa##j.x * ua.x + xa##j.y * ua.y + xa##j.z * ua.z + \
                 xa##j.w * ua.w + xb##j.x * ub2.x + xb##j.y * ub2.y;

__global__ __launch_bounds__(256, 4) void ga_stream(
    const float* __restrict__ h, const void* __restrict__ mask,
    const float* __restrict__ u, const float* __restrict__ c,
    const int* __restrict__ flag,
    float* __restrict__ pm, float* __restrict__ ps, float* __restrict__ pa)
{
    const int blk = blockIdx.x;           // 1024 blocks
    const int b = blk >> 5;               // batch
    const int chunk = blk & (CHUNKS - 1);
    const int wave = threadIdx.x >> 6;
    const int lane = threadIdx.x & 63;

    // u fragment: float4 over elems [0,256), float2 over [256,384)
    const float* ubase = u + b * DD;
    const float4 ua  = *(const float4*)(ubase + 4 * lane);
    const float2 ub2 = *(const float2*)(ubase + 256 + 2 * lane);
    const float cc = c[b];

    const int n0 = chunk * RPB + wave * RPW;
    const size_t rowbase = (size_t)b * NN + n0;
    const float* hb = h + rowbase * DD;

    // Gather this wave's 64 mask bits -> ballot, compact indices into LDS
    const int fm = *flag;
    int myMask;
    const size_t mi = rowbase + lane;
    if (fm == 0)      myMask = ((const int*)mask)[mi] != 0;
    else if (fm == 1) myMask = ((const unsigned*)mask)[mi] != 0u;
    else              myMask = ((const unsigned char*)mask)[mi] != 0;
    const unsigned long long mbits = __ballot(myMask);
    const int cnt = __popcll(mbits);
    const int pos = __popcll(mbits & ((1ull << lane) - 1ull));

    __shared__ int wlist[NWAVES][64];
    __shared__ float lm[NWAVES], lss[NWAVES];
    __shared__ float la[NWAVES][DD];

    if (myMask) wlist[wave][pos] = lane;   // wave-synchronous, no barrier needed

    float m = -INFINITY, s = 0.f;
    float a0 = 0.f, a1 = 0.f, a2 = 0.f, a3 = 0.f, a4 = 0.f, a5 = 0.f;

    for (int base = 0; base < cnt; base += 8) {
        GA_LOAD(0) GA_LOAD(1) GA_LOAD(2) GA_LOAD(3)
        GA_LOAD(4) GA_LOAD(5) GA_LOAD(6) GA_LOAD(7)

        GA_DOT(0) GA_DOT(1) GA_DOT(2) GA_DOT(3)
        GA_DOT(4) GA_DOT(5) GA_DOT(6) GA_DOT(7)

#pragma unroll
        for (int off = 32; off; off >>= 1) {
            d0 += __shfl_xor(d0, off, 64);
            d1 += __shfl_xor(d1, off, 64);
            d2 += __shfl_xor(d2, off, 64);
            d3 += __shfl_xor(d3, off, 64);
            d4 += __shfl_xor(d4, off, 64);
            d5 += __shfl_xor(d5, off, 64);
            d6 += __shfl_xor(d6, off, 64);
            d7 += __shfl_xor(d7, off, 64);
        }

        const int nv = cnt - base;  // >= 1
        const float s0v = d0 + cc;
        const float s1v = d1 + cc, s2v = d2 + cc, s3v = d3 + cc;
        const float s4v = d4 + cc, s5v = d5 + cc, s6v = d6 + cc, s7v = d7 + cc;

        const float t1 = (1 < nv) ? s1v : -INFINITY;
        const float t2 = (2 < nv) ? s2v : -INFINITY;
        const float t3 = (3 < nv) ? s3v : -INFINITY;
        const float t4 = (4 < nv) ? s4v : -INFINITY;
        const float t5 = (5 < nv) ? s5v : -INFINITY;
        const float t6 = (6 < nv) ? s6v : -INFINITY;
        const float t7 = (7 < nv) ? s7v : -INFINITY;
        const float M8 = fmaxf(fmaxf(fmaxf(s0v, t1), fmaxf(t2, t3)),
                               fmaxf(fmaxf(t4, t5), fmaxf(t6, t7)));
        const float mn = fmaxf(m, M8);
        const float f = __expf(m - mn);  // first iter: exp(-inf)=0, s/a are 0 anyway
        m = mn;
        s *= f;
        a0 *= f; a1 *= f; a2 *= f; a3 *= f; a4 *= f; a5 *= f;

        const float p0 = __expf(s0v - m);
        const float p1 = (1 < nv) ? __expf(s1v - m) : 0.f;
        const float p2 = (2 < nv) ? __expf(s2v - m) : 0.f;
        const float p3 = (3 < nv) ? __expf(s3v - m) : 0.f;
        const float p4 = (4 < nv) ? __expf(s4v - m) : 0.f;
        const float p5 = (5 < nv) ? __expf(s5v - m) : 0.f;
        const float p6 = (6 < nv) ? __expf(s6v - m) : 0.f;
        const float p7 = (7 < nv) ? __expf(s7v - m) : 0.f;

        s += ((p0 + p1) + (p2 + p3)) + ((p4 + p5) + (p6 + p7));

        a0 += p0 * xa0.x + p1 * xa1.x + p2 * xa2.x + p3 * xa3.x +
              p4 * xa4.x + p5 * xa5.x + p6 * xa6.x + p7 * xa7.x;
        a1 += p0 * xa0.y + p1 * xa1.y + p2 * xa2.y + p3 * xa3.y +
              p4 * xa4.y + p5 * xa5.y + p6 * xa6.y + p7 * xa7.y;
        a2 += p0 * xa0.z + p1 * xa1.z + p2 * xa2.z + p3 * xa3.z +
              p4 * xa4.z + p5 * xa5.z + p6 * xa6.z + p7 * xa7.z;
        a3 += p0 * xa0.w + p1 * xa1.w + p2 * xa2.w + p3 * xa3.w +
              p4 * xa4.w + p5 * xa5.w + p6 * xa6.w + p7 * xa7.w;
        a4 += p0 * xb0.x + p1 * xb1.x + p2 * xb2.x + p3 * xb3.x +
              p4 * xb4.x + p5 * xb5.x + p6 * xb6.x + p7 * xb7.x;
        a5 += p0 * xb0.y + p1 * xb1.y + p2 * xb2.y + p3 * xb3.y +
              p4 * xb4.y + p5 * xb5.y + p6 * xb6.y + p7 * xb7.y;
    }

    // Accumulator layout: a0..a3 = elems 4*lane+{0..3}; a4,a5 = 256+2*lane+{0,1}
    *(float4*)&la[wave][4 * lane] = make_float4(a0, a1, a2, a3);
    *(float2*)&la[wave][256 + 2 * lane] = make_float2(a4, a5);
    if (lane == 0) { lm[wave] = m; lss[wave] = s; }
    __syncthreads();

    const float M = fmaxf(fmaxf(lm[0], lm[1]), fmaxf(lm[2], lm[3]));
    const float w0 = (lm[0] == -INFINITY) ? 0.f : __expf(lm[0] - M);
    const float w1 = (lm[1] == -INFINITY) ? 0.f : __expf(lm[1] - M);
    const float w2 = (lm[2] == -INFINITY) ? 0.f : __expf(lm[2] - M);
    const float w3 = (lm[3] == -INFINITY) ? 0.f : __expf(lm[3] - M);
    const float S = w0 * lss[0] + w1 * lss[1] + w2 * lss[2] + w3 * lss[3];
    if (threadIdx.x == 0) { pm[blk] = M; ps[blk] = S; }
    for (int idx = threadIdx.x; idx < DD; idx += 256) {
        pa[(size_t)blk * DD + idx] =
            w0 * la[0][idx] + w1 * la[1][idx] + w2 * la[2][idx] + w3 * la[3][idx];
    }
}

// ---------------------------------------------------------------------------
// Kernel C: per batch, reduce 32 partials -> a_norm[384]; nws = a_norm@Wv+bv;
// z=[nws,target]; out = relu(z@W1+b1)@W2+b2.
// ---------------------------------------------------------------------------
__global__ __launch_bounds__(128) void ga_finish(
    const float* __restrict__ target,
    const float* __restrict__ Wv, const float* __restrict__ bv,
    const float* __restrict__ W1, const float* __restrict__ b1,
    const float* __restrict__ W2, const float* __restrict__ b2,
    const float* __restrict__ pm, const float* __restrict__ ps,
    const float* __restrict__ pa, float* __restrict__ out)
{
    const int b = blockIdx.x;   // 32 blocks
    const int t = threadIdx.x;  // 128 threads

    __shared__ float an[DD];
    __shared__ float z[LL + DD];
    __shared__ float hid[LL];

    float M = -INFINITY;
#pragma unroll
    for (int i = 0; i < CHUNKS; ++i) M = fmaxf(M, pm[b * CHUNKS + i]);
    float wgt[CHUNKS];
    float S = 0.f;
#pragma unroll
    for (int i = 0; i < CHUNKS; ++i) {
        float mi = pm[b * CHUNKS + i];
        float w = (mi == -INFINITY) ? 0.f : __expf(mi - M);
        wgt[i] = w;
        S += w * ps[b * CHUNKS + i];
    }
    const float invS = 1.f / S;

    for (int d = t; d < DD; d += LL) {
        float av = 0.f;
#pragma unroll
        for (int i = 0; i < CHUNKS; ++i)
            av += wgt[i] * pa[(size_t)(b * CHUNKS + i) * DD + d];
        an[d] = av * invS;
    }
    __syncthreads();

    float acc = bv[t];
#pragma unroll 4
    for (int d = 0; d < DD; ++d) acc += an[d] * Wv[d * LL + t];
    z[t] = acc;
    for (int j = t; j < DD; j += LL) z[LL + j] = target[b * DD + j];
    __syncthreads();

    float hacc = b1[t];
#pragma unroll 4
    for (int j = 0; j < LL + DD; ++j) hacc += z[j] * W1[j * LL + t];
    hid[t] = fmaxf(hacc, 0.f);
    __syncthreads();

    float oacc = b2[t];
#pragma unroll 4
    for (int j = 0; j < LL; ++j) oacc += hid[j] * W2[j * LL + t];
    out[b * LL + t] = oacc;
}

// ---------------------------------------------------------------------------
extern "C" void kernel_launch(void* const* d_in, const int* in_sizes, int n_in,
                              void* d_out, int out_size, void* d_ws, size_t ws_size,
                              hipStream_t stream)
{
    const float* target = (const float*)d_in[0];
    const float* h      = (const float*)d_in[1];
    const void*  mask   = d_in[2];
    const float* Wq = (const float*)d_in[3];
    const float* bq = (const float*)d_in[4];
    const float* Wk = (const float*)d_in[5];
    const float* bk = (const float*)d_in[6];
    const float* Wv = (const float*)d_in[7];
    const float* bv = (const float*)d_in[8];
    const float* W1 = (const float*)d_in[9];
    const float* b1 = (const float*)d_in[10];
    const float* W2 = (const float*)d_in[11];
    const float* b2 = (const float*)d_in[12];
    float* out = (float*)d_out;

    float* ws = (float*)d_ws;
    int*   flag = (int*)d_ws;
    float* u  = ws + 64;
    float* c  = u + NB * DD;
    float* pm = c + NB;
    float* ps = pm + NB * CHUNKS;
    float* pa = ps + NB * CHUNKS;

    hipLaunchKernelGGL(ga_prep, dim3(NB), dim3(DD), 0, stream,
                       target, Wq, bq, Wk, bk, mask, u, c, flag);
    hipLaunchKernelGGL(ga_stream, dim3(NB * CHUNKS), dim3(256), 0, stream,
                       h, mask, u, c, flag, pm, ps, pa);
    hipLaunchKernelGGL(ga_finish, dim3(NB), dim3(LL), 0, stream,
                       target, Wv, bv, W1, b1, W2, b2, pm, ps, pa, out);
}